// Round 15
// baseline (23.423 us; speedup 1.0000x reference)
//
#include <hip/hip_runtime.h>

// Fasttext: out[b,t,p] = W @ embed[ids[b,t]] + b, masked t < seq_lengths[b]
// VOCAB=200000, E=300, P=128, B=16, S=2048, BS=32768
//
// R17: halve LDS-B traffic + block count via bv-register-reuse.
// Wave = 32 tokens x 64 cols: two token-halves (av_lo/av_hi) share every
// ds_read_b128 B-fragment (2 MFMAs per bv). Block = 128 tok x 64-col half,
// 256 thr / 4 waves; grid 512 (256 tiles x 2 halves), 2 blocks/CU.
// LDS-B per CU-gen: 640KB -> 320KB; W-staging L2 traffic halves; half the
// per-block latency chains. VGPR ~140 is fine at 8 waves/CU (<=256).
// Keeps: XCD pairing (slots d,d+8 = same tile's halves -> same XCD ->
// duplicate gather L2-hits), W-first staging order (ds_writes wait only on
// W loads, A-gather stays in flight), balanced zero-fill, exact-bounds
// tails, epilogue per-row masking.

#define E 300
#define P 128
#define S 2048
#define BS 32768
#define TM 128
#define NB 16

typedef short bf16x8 __attribute__((ext_vector_type(8)));
typedef short bf16x4 __attribute__((ext_vector_type(4)));
typedef float f32x4 __attribute__((ext_vector_type(4)));

__device__ inline unsigned short f32_bf16_fast(float f) {
    unsigned int u = __builtin_bit_cast(unsigned int, f);
    return (unsigned short)((u + 0x8000u) >> 16);
}
__device__ inline bf16x8 cvt8(f32x4 a, f32x4 b) {
    bf16x8 r;
    r[0] = (short)f32_bf16_fast(a[0]); r[1] = (short)f32_bf16_fast(a[1]);
    r[2] = (short)f32_bf16_fast(a[2]); r[3] = (short)f32_bf16_fast(a[3]);
    r[4] = (short)f32_bf16_fast(b[0]); r[5] = (short)f32_bf16_fast(b[1]);
    r[6] = (short)f32_bf16_fast(b[2]); r[7] = (short)f32_bf16_fast(b[3]);
    return r;
}
__device__ inline bf16x4 cvt4(f32x4 a) {
    bf16x4 r;
    r[0] = (short)f32_bf16_fast(a[0]); r[1] = (short)f32_bf16_fast(a[1]);
    r[2] = (short)f32_bf16_fast(a[2]); r[3] = (short)f32_bf16_fast(a[3]);
    return r;
}

__global__ __launch_bounds__(256) void ft_main(
    const int* __restrict__ ids, const int* __restrict__ seqlen,
    const float* __restrict__ embed, const float* __restrict__ Wf,
    const float* __restrict__ bias, float* __restrict__ out)
{
    // W-half, bf16, fragment-major: off(s,ni,fr,kg,h) =
    //   ((s*4+ni)*16+fr)*64 + kg*16 + h*8  -> 40960 B
    __shared__ unsigned char Wl[40960];

    const int tid  = threadIdx.x;
    const int wave = tid >> 6, lane = tid & 63;
    const int fr   = lane & 15, kg = lane >> 4;

    // XCD pairing over 512 slots: (d, d+8) -> same tile, same slot mod 8
    const int d   = blockIdx.x;                  // [0, 512)
    const int grp = d >> 4, sub = d & 15;
    const int rt  = grp * 8 + (sub & 7);         // tile [0, 256)
    const int ch  = sub >> 3;                    // col half

    const int tok0 = rt * TM;
    const int bi0  = tok0 >> 11;                 // batch (128 | 2048)
    const int t0   = tok0 & (S - 1);

    // hoist: issue id + sl0 loads immediately (2-deep chain to gather)
    const int r_lo  = tok0 + wave * 32 + fr;
    const int id_lo = ids[r_lo];
    const int id_hi = ids[r_lo + 16];
    const int sl0   = seqlen[bi0];

    if (sl0 > t0) {                              // ---- real GEMM block ----
        // -- stage W rows [ch*64, +64) -> LDS fragment-major (W loads FIRST) --
        const int R0 = ch * 64;
        #pragma unroll
        for (int i = 0; i < 20; ++i) {
            int g4 = tid + i * 256;              // [0, 5120) quads
            int r  = g4 / 80;
            int c4 = g4 - r * 80;
            int c0 = c4 * 4;                     // {0,4,...,316}
            f32x4 v = {0.f, 0.f, 0.f, 0.f};
            if (c0 < 300)                        // c0 <= 296: reads 296..299 exact
                v = *(const f32x4*)(Wf + (long long)(R0 + r) * E + c0);
            int s   = c0 >> 5;
            int kgg = (c0 & 31) >> 3;
            int h   = (c0 >> 2) & 1;
            int ni  = r >> 4;
            int fr2 = r & 15;
            int off = (((s * 4 + ni) * 16 + fr2) << 6) + (kgg << 4) + (h << 3);
            *(bf16x4*)(Wl + off) = cvt4(v);
        }

        // -- A gather: two rows per lane, 38 independent loads --
        const float* __restrict__ rpL = embed + (long long)id_lo * E;
        const float* __restrict__ rpH = embed + (long long)id_hi * E;

        bf16x8 avL[10], avH[10];
        #pragma unroll
        for (int s = 0; s < 9; ++s) {
            const int kb = s * 32 + kg * 8;      // <= 280; ends 287 < 300
            f32x4 a0 = *(const f32x4*)(rpL + kb);
            f32x4 a1 = *(const f32x4*)(rpL + kb + 4);
            f32x4 b0 = *(const f32x4*)(rpH + kb);
            f32x4 b1 = *(const f32x4*)(rpH + kb + 4);
            avL[s] = cvt8(a0, a1);
            avH[s] = cvt8(b0, b1);
        }
        {   // tail: valid k 288..299, exact bounds
            f32x4 z4 = {0.f, 0.f, 0.f, 0.f};
            f32x4 a0 = z4, a1 = z4, b0 = z4, b1 = z4;
            if (kg == 0) {
                a0 = *(const f32x4*)(rpL + 288); a1 = *(const f32x4*)(rpL + 292);
                b0 = *(const f32x4*)(rpH + 288); b1 = *(const f32x4*)(rpH + 292);
            } else if (kg == 1) {
                a0 = *(const f32x4*)(rpL + 296);
                b0 = *(const f32x4*)(rpH + 296);
            }
            avL[9] = cvt8(a0, a1);
            avH[9] = cvt8(b0, b1);
        }
        __syncthreads();

        // -- MFMA: 10 k-steps x 4 ni; each bv feeds BOTH token-halves --
        f32x4 aL[4], aH[4];
        #pragma unroll
        for (int ni = 0; ni < 4; ++ni) {
            aL[ni] = (f32x4){0.f, 0.f, 0.f, 0.f};
            aH[ni] = (f32x4){0.f, 0.f, 0.f, 0.f};
        }
        #pragma unroll
        for (int s = 0; s < 10; ++s) {
            #pragma unroll
            for (int ni = 0; ni < 4; ++ni) {
                bf16x8 bv = *(const bf16x8*)(Wl + ((((s * 4 + ni) * 16 + fr) << 6) + (kg << 4)));
                aL[ni] = __builtin_amdgcn_mfma_f32_16x16x32_bf16(avL[s], bv, aL[ni], 0, 0, 0);
                aH[ni] = __builtin_amdgcn_mfma_f32_16x16x32_bf16(avH[s], bv, aH[ni], 0, 0, 0);
            }
        }

        // -- epilogue: +bias, per-row mask, store both halves --
        // C/D layout: col(=W row -> P) = lane&15, row(=token) = (lane>>4)*4 + j
        float bs[4];
        #pragma unroll
        for (int ni = 0; ni < 4; ++ni) bs[ni] = bias[ch * 64 + ni * 16 + fr];

        #pragma unroll
        for (int j = 0; j < 4; ++j) {
            int tokL = tok0 + wave * 32 + kg * 4 + j;
            int tokH = tokL + 16;
            bool vL = ((tokL & (S - 1)) < sl0);
            bool vH = ((tokH & (S - 1)) < sl0);
            #pragma unroll
            for (int ni = 0; ni < 4; ++ni) {
                float xL = vL ? (aL[ni][j] + bs[ni]) : 0.0f;
                float xH = vH ? (aH[ni][j] + bs[ni]) : 0.0f;
                out[(long long)tokL * P + ch * 64 + ni * 16 + fr] = xL;
                out[(long long)tokH * P + ch * 64 + ni * 16 + fr] = xH;
            }
        }
    }

    // ---- zero-fill share (ALL 512 blocks, exactly even split) ----
    // masked region per batch: tokens [rb*128, 2048), rb = ceil(sl/128)
    int rb0  = (seqlen[0]  + 127) >> 7,  rb1  = (seqlen[1]  + 127) >> 7,
        rb2  = (seqlen[2]  + 127) >> 7,  rb3  = (seqlen[3]  + 127) >> 7,
        rb4  = (seqlen[4]  + 127) >> 7,  rb5  = (seqlen[5]  + 127) >> 7,
        rb6  = (seqlen[6]  + 127) >> 7,  rb7  = (seqlen[7]  + 127) >> 7,
        rb8  = (seqlen[8]  + 127) >> 7,  rb9  = (seqlen[9]  + 127) >> 7,
        rb10 = (seqlen[10] + 127) >> 7,  rb11 = (seqlen[11] + 127) >> 7,
        rb12 = (seqlen[12] + 127) >> 7,  rb13 = (seqlen[13] + 127) >> 7,
        rb14 = (seqlen[14] + 127) >> 7,  rb15 = (seqlen[15] + 127) >> 7;
    int zp0 = 0;
    int zp1  = zp0  + ((S - (rb0  << 7)) << 5);
    int zp2  = zp1  + ((S - (rb1  << 7)) << 5);
    int zp3  = zp2  + ((S - (rb2  << 7)) << 5);
    int zp4  = zp3  + ((S - (rb3  << 7)) << 5);
    int zp5  = zp4  + ((S - (rb4  << 7)) << 5);
    int zp6  = zp5  + ((S - (rb5  << 7)) << 5);
    int zp7  = zp6  + ((S - (rb6  << 7)) << 5);
    int zp8  = zp7  + ((S - (rb7  << 7)) << 5);
    int zp9  = zp8  + ((S - (rb8  << 7)) << 5);
    int zp10 = zp9  + ((S - (rb9  << 7)) << 5);
    int zp11 = zp10 + ((S - (rb10 << 7)) << 5);
    int zp12 = zp11 + ((S - (rb11 << 7)) << 5);
    int zp13 = zp12 + ((S - (rb12 << 7)) << 5);
    int zp14 = zp13 + ((S - (rb13 << 7)) << 5);
    int zp15 = zp14 + ((S - (rb14 << 7)) << 5);
    int zp16 = zp15 + ((S - (rb15 << 7)) << 5);

    const int zq  = zp16;
    const int per = (zq + 511) >> 9;             // quads per block (512 blocks)
    int q0 = d * per;
    int q1 = q0 + per; if (q1 > zq) q1 = zq;

    for (int q = q0 + tid; q < q1; q += 256) {
        int base = 0, tk0 = 0;
        #define ZSEL(BB, LO, HI, RB) \
            if (q >= (LO) && q < (HI)) { base = (LO); tk0 = ((BB) << 11) + ((RB) << 7); }
        ZSEL(0,  zp0,  zp1,  rb0)  ZSEL(1,  zp1,  zp2,  rb1)
        ZSEL(2,  zp2,  zp3,  rb2)  ZSEL(3,  zp3,  zp4,  rb3)
        ZSEL(4,  zp4,  zp5,  rb4)  ZSEL(5,  zp5,  zp6,  rb5)
        ZSEL(6,  zp6,  zp7,  rb6)  ZSEL(7,  zp7,  zp8,  rb7)
        ZSEL(8,  zp8,  zp9,  rb8)  ZSEL(9,  zp9,  zp10, rb9)
        ZSEL(10, zp10, zp11, rb10) ZSEL(11, zp11, zp12, rb11)
        ZSEL(12, zp12, zp13, rb12) ZSEL(13, zp13, zp14, rb13)
        ZSEL(14, zp14, zp15, rb14) ZSEL(15, zp15, zp16, rb15)
        #undef ZSEL
        int lq    = q - base;
        int token = tk0 + (lq >> 5);
        int c     = (lq & 31) << 2;
        *(f32x4*)(out + (long long)token * P + c) = (f32x4){0.f, 0.f, 0.f, 0.f};
    }
}

extern "C" void kernel_launch(void* const* d_in, const int* in_sizes, int n_in,
                              void* d_out, int out_size, void* d_ws, size_t ws_size,
                              hipStream_t stream) {
    const int*   ids    = (const int*)d_in[0];
    const int*   sl     = (const int*)d_in[1];
    const float* embed  = (const float*)d_in[2];
    const float* W      = (const float*)d_in[3];
    const float* bias   = (const float*)d_in[4];
    float*       out    = (float*)d_out;

    ft_main<<<(BS / TM) * 2, 256, 0, stream>>>(ids, sl, embed, W, bias, out);
}

// Round 16
// 20.201 us; speedup vs baseline: 1.1595x; 1.1595x over previous
//
#include <hip/hip_runtime.h>

// Fasttext: out[b,t,p] = W @ embed[ids[b,t]] + b, masked t < seq_lengths[b]
// VOCAB=200000, E=300, P=128, B=16, S=2048, BS=32768
//
// R18 = R15 (best, 19.96us) + __launch_bounds__(256,5): cap VGPR at 102 to
// lift occupancy 4 -> 5 waves/SIMD (16 -> 20 waves/CU). R9/R11/R17 tripled-
// confirmed waves/CU is the governing variable for this latency-bound
// gather (~3.5us per halving); +25% waves predicts ~1-1.5us.
// Everything else identical to R15: real tiles packed into first 2R slots
// with XCD pairing (slots d,d+8 = one tile's col-halves -> same XCD ->
// duplicate gather L2-hits), W-half fragment-major in 40KB LDS staged
// BEFORE the A-gather, av[10] hoisted (19 independent loads/lane),
// exact-bounds tails, balanced zero-fill across all 1024 blocks.

#define E 300
#define P 128
#define S 2048
#define BS 32768
#define TM 64
#define NB 16

typedef short bf16x8 __attribute__((ext_vector_type(8)));
typedef short bf16x4 __attribute__((ext_vector_type(4)));
typedef float f32x4 __attribute__((ext_vector_type(4)));

__device__ inline unsigned short f32_bf16_fast(float f) {
    unsigned int u = __builtin_bit_cast(unsigned int, f);
    return (unsigned short)((u + 0x8000u) >> 16);
}
__device__ inline bf16x8 cvt8(f32x4 a, f32x4 b) {
    bf16x8 r;
    r[0] = (short)f32_bf16_fast(a[0]); r[1] = (short)f32_bf16_fast(a[1]);
    r[2] = (short)f32_bf16_fast(a[2]); r[3] = (short)f32_bf16_fast(a[3]);
    r[4] = (short)f32_bf16_fast(b[0]); r[5] = (short)f32_bf16_fast(b[1]);
    r[6] = (short)f32_bf16_fast(b[2]); r[7] = (short)f32_bf16_fast(b[3]);
    return r;
}
__device__ inline bf16x4 cvt4(f32x4 a) {
    bf16x4 r;
    r[0] = (short)f32_bf16_fast(a[0]); r[1] = (short)f32_bf16_fast(a[1]);
    r[2] = (short)f32_bf16_fast(a[2]); r[3] = (short)f32_bf16_fast(a[3]);
    return r;
}

__global__ __launch_bounds__(256, 5) void ft_main(
    const int* __restrict__ ids, const int* __restrict__ seqlen,
    const float* __restrict__ embed, const float* __restrict__ Wf,
    const float* __restrict__ bias, float* __restrict__ out)
{
    __shared__ unsigned char Wl[40960];

    const int tid  = threadIdx.x;
    const int wave = tid >> 6, lane = tid & 63;
    const int fr   = lane & 15, kg = lane >> 4;
    const int d    = blockIdx.x;                 // [0, 1024)

    // slot -> (real-tile index rt, col-half ch); pair (d, d+8) same XCD
    const int grp = d >> 4, sub = d & 15;
    const int rt  = grp * 8 + (sub & 7);         // [0, 512)
    const int ch  = sub >> 3;

    // locate rt among real tiles: batch b, local tile lt (register-only scan)
    int b = -1, lt = 0, acc = 0;
    #pragma unroll
    for (int bb = 0; bb < NB; ++bb) {
        int rb = (seqlen[bb] + 63) >> 6;         // real tiles in batch bb
        if (rt >= acc && rt < acc + rb) { b = bb; lt = rt - acc; }
        acc += rb;
    }

    if (b >= 0) {                                 // ---- real GEMM block ----
        const int tok0 = (b << 11) + (lt << 6);
        const int sl0  = seqlen[b];

        // -- stage W rows [ch*64, ch*64+64) -> LDS bf16 fragment-major (FIRST) --
        const int R0 = ch * 64;
        #pragma unroll
        for (int i = 0; i < 20; ++i) {
            int g4 = tid + i * 256;               // [0, 5120) quads
            int r  = g4 / 80;
            int c4 = g4 - r * 80;
            int c0 = c4 * 4;                      // {0,4,...,316}
            f32x4 v = {0.f, 0.f, 0.f, 0.f};
            if (c0 < 300)                         // c0 <= 296: reads 296..299 exact
                v = *(const f32x4*)(Wf + (long long)(R0 + r) * E + c0);
            int s   = c0 >> 5;
            int kgg = (c0 & 31) >> 3;
            int h   = (c0 >> 2) & 1;
            int ni  = r >> 4;
            int fr2 = r & 15;
            int off = (((s * 4 + ni) * 16 + fr2) << 6) + (kgg << 4) + (h << 3);
            *(bf16x4*)(Wl + off) = cvt4(v);
        }

        // -- A: gather this lane's row fragments (19 independent loads) --
        const int token_a = tok0 + wave * 16 + fr;
        const int id = ids[token_a];
        const float* __restrict__ rp = embed + (long long)id * E;

        bf16x8 av[10];
        #pragma unroll
        for (int s = 0; s < 9; ++s) {
            const int kb = s * 32 + kg * 8;       // <= 280; ends 287 < 300
            f32x4 f0 = *(const f32x4*)(rp + kb);
            f32x4 f1 = *(const f32x4*)(rp + kb + 4);
            av[s] = cvt8(f0, f1);
        }
        {   // tail: valid k 288..299, exact bounds
            f32x4 z4 = {0.f, 0.f, 0.f, 0.f};
            f32x4 f0 = z4, f1 = z4;
            if (kg == 0)      { f0 = *(const f32x4*)(rp + 288); f1 = *(const f32x4*)(rp + 292); }
            else if (kg == 1) { f0 = *(const f32x4*)(rp + 296); }
            av[9] = cvt8(f0, f1);
        }
        __syncthreads();

        // -- MFMA: 10 k-steps x 4 ni, B from LDS (conflict-free b128) --
        f32x4 acc4[4];
        #pragma unroll
        for (int ni = 0; ni < 4; ++ni) acc4[ni] = (f32x4){0.f, 0.f, 0.f, 0.f};

        #pragma unroll
        for (int s = 0; s < 10; ++s) {
            #pragma unroll
            for (int ni = 0; ni < 4; ++ni) {
                bf16x8 bv = *(const bf16x8*)(Wl + ((((s * 4 + ni) * 16 + fr) << 6) + (kg << 4)));
                acc4[ni] = __builtin_amdgcn_mfma_f32_16x16x32_bf16(av[s], bv, acc4[ni], 0, 0, 0);
            }
        }

        // -- epilogue: +bias, per-row seq-mask, store --
        // C/D layout: col(=W row -> P) = lane&15, row(=token) = (lane>>4)*4 + j
        float bs[4];
        #pragma unroll
        for (int ni = 0; ni < 4; ++ni) bs[ni] = bias[ch * 64 + ni * 16 + fr];

        #pragma unroll
        for (int j = 0; j < 4; ++j) {
            int orow  = wave * 16 + kg * 4 + j;
            int token = tok0 + orow;
            int t     = token & (S - 1);
            bool valid = (t < sl0);
            #pragma unroll
            for (int ni = 0; ni < 4; ++ni) {
                float v = valid ? (acc4[ni][j] + bs[ni]) : 0.0f;
                out[(long long)token * P + ch * 64 + ni * 16 + fr] = v;
            }
        }
    }

    // ---- zero-fill share (ALL blocks, exactly even split) ----
    int rb0  = (seqlen[0]  + 63) >> 6,  rb1  = (seqlen[1]  + 63) >> 6,
        rb2  = (seqlen[2]  + 63) >> 6,  rb3  = (seqlen[3]  + 63) >> 6,
        rb4  = (seqlen[4]  + 63) >> 6,  rb5  = (seqlen[5]  + 63) >> 6,
        rb6  = (seqlen[6]  + 63) >> 6,  rb7  = (seqlen[7]  + 63) >> 6,
        rb8  = (seqlen[8]  + 63) >> 6,  rb9  = (seqlen[9]  + 63) >> 6,
        rb10 = (seqlen[10] + 63) >> 6,  rb11 = (seqlen[11] + 63) >> 6,
        rb12 = (seqlen[12] + 63) >> 6,  rb13 = (seqlen[13] + 63) >> 6,
        rb14 = (seqlen[14] + 63) >> 6,  rb15 = (seqlen[15] + 63) >> 6;
    int zp0 = 0;
    int zp1  = zp0  + ((S - (rb0  << 6)) << 5);
    int zp2  = zp1  + ((S - (rb1  << 6)) << 5);
    int zp3  = zp2  + ((S - (rb2  << 6)) << 5);
    int zp4  = zp3  + ((S - (rb3  << 6)) << 5);
    int zp5  = zp4  + ((S - (rb4  << 6)) << 5);
    int zp6  = zp5  + ((S - (rb5  << 6)) << 5);
    int zp7  = zp6  + ((S - (rb6  << 6)) << 5);
    int zp8  = zp7  + ((S - (rb7  << 6)) << 5);
    int zp9  = zp8  + ((S - (rb8  << 6)) << 5);
    int zp10 = zp9  + ((S - (rb9  << 6)) << 5);
    int zp11 = zp10 + ((S - (rb10 << 6)) << 5);
    int zp12 = zp11 + ((S - (rb11 << 6)) << 5);
    int zp13 = zp12 + ((S - (rb12 << 6)) << 5);
    int zp14 = zp13 + ((S - (rb13 << 6)) << 5);
    int zp15 = zp14 + ((S - (rb14 << 6)) << 5);
    int zp16 = zp15 + ((S - (rb15 << 6)) << 5);

    const int zq  = zp16;
    const int per = (zq + 1023) >> 10;           // quads per block
    int q0 = d * per;
    int q1 = q0 + per; if (q1 > zq) q1 = zq;

    for (int q = q0 + tid; q < q1; q += 256) {
        int base = 0, tk0 = 0;
        #define ZSEL(BB, LO, HI, RB) \
            if (q >= (LO) && q < (HI)) { base = (LO); tk0 = ((BB) << 11) + ((RB) << 6); }
        ZSEL(0,  zp0,  zp1,  rb0)  ZSEL(1,  zp1,  zp2,  rb1)
        ZSEL(2,  zp2,  zp3,  rb2)  ZSEL(3,  zp3,  zp4,  rb3)
        ZSEL(4,  zp4,  zp5,  rb4)  ZSEL(5,  zp5,  zp6,  rb5)
        ZSEL(6,  zp6,  zp7,  rb6)  ZSEL(7,  zp7,  zp8,  rb7)
        ZSEL(8,  zp8,  zp9,  rb8)  ZSEL(9,  zp9,  zp10, rb9)
        ZSEL(10, zp10, zp11, rb10) ZSEL(11, zp11, zp12, rb11)
        ZSEL(12, zp12, zp13, rb12) ZSEL(13, zp13, zp14, rb13)
        ZSEL(14, zp14, zp15, rb14) ZSEL(15, zp15, zp16, rb15)
        #undef ZSEL
        int lq    = q - base;
        int token = tk0 + (lq >> 5);
        int c     = (lq & 31) << 2;
        *(f32x4*)(out + (long long)token * P + c) = (f32x4){0.f, 0.f, 0.f, 0.f};
    }
}

extern "C" void kernel_launch(void* const* d_in, const int* in_sizes, int n_in,
                              void* d_out, int out_size, void* d_ws, size_t ws_size,
                              hipStream_t stream) {
    const int*   ids    = (const int*)d_in[0];
    const int*   sl     = (const int*)d_in[1];
    const float* embed  = (const float*)d_in[2];
    const float* W      = (const float*)d_in[3];
    const float* bias   = (const float*)d_in[4];
    float*       out    = (float*)d_out;

    ft_main<<<(BS / TM) * 2, 256, 0, stream>>>(ids, sl, embed, W, bias, out);
}

// Round 17
// 18.758 us; speedup vs baseline: 1.2487x; 1.0769x over previous
//
#include <hip/hip_runtime.h>

// Fasttext: out[b,t,p] = W @ embed[ids[b,t]] + b, masked t < seq_lengths[b]
// VOCAB=200000, E=300, P=128, B=16, S=2048, BS=32768
//
// R20 = R15 + raw-first gather burst. R9 vs R17 showed per-wave load depth
// is an independent lever (-2.9us at fixed waves/CU); R18 showed a VGPR cap
// kills depth. Here: ALL 20 gather loads (18 full + 2 tail) issued as one
// program-ordered burst into raw f32x4 registers with NO interleaved VALU,
// cvt to bf16 afterward. VGPR ~150 -> 12 waves/CU x ~19-deep = ~230
// in-flight loads/CU vs R15's ~96. Everything else = R15: packed real
// tiles + XCD pairing (slots d,d+8 same tile -> same XCD -> dup gather
// L2-hits), W-half fragment-major 40KB LDS staged first, balanced
// zero-fill, exact-bounds tails.

#define E 300
#define P 128
#define S 2048
#define BS 32768
#define TM 64
#define NB 16

typedef short bf16x8 __attribute__((ext_vector_type(8)));
typedef short bf16x4 __attribute__((ext_vector_type(4)));
typedef float f32x4 __attribute__((ext_vector_type(4)));

__device__ inline unsigned short f32_bf16_fast(float f) {
    unsigned int u = __builtin_bit_cast(unsigned int, f);
    return (unsigned short)((u + 0x8000u) >> 16);
}
__device__ inline bf16x8 cvt8(f32x4 a, f32x4 b) {
    bf16x8 r;
    r[0] = (short)f32_bf16_fast(a[0]); r[1] = (short)f32_bf16_fast(a[1]);
    r[2] = (short)f32_bf16_fast(a[2]); r[3] = (short)f32_bf16_fast(a[3]);
    r[4] = (short)f32_bf16_fast(b[0]); r[5] = (short)f32_bf16_fast(b[1]);
    r[6] = (short)f32_bf16_fast(b[2]); r[7] = (short)f32_bf16_fast(b[3]);
    return r;
}
__device__ inline bf16x4 cvt4(f32x4 a) {
    bf16x4 r;
    r[0] = (short)f32_bf16_fast(a[0]); r[1] = (short)f32_bf16_fast(a[1]);
    r[2] = (short)f32_bf16_fast(a[2]); r[3] = (short)f32_bf16_fast(a[3]);
    return r;
}

__global__ __launch_bounds__(256) void ft_main(
    const int* __restrict__ ids, const int* __restrict__ seqlen,
    const float* __restrict__ embed, const float* __restrict__ Wf,
    const float* __restrict__ bias, float* __restrict__ out)
{
    __shared__ unsigned char Wl[40960];

    const int tid  = threadIdx.x;
    const int wave = tid >> 6, lane = tid & 63;
    const int fr   = lane & 15, kg = lane >> 4;
    const int d    = blockIdx.x;                 // [0, 1024)

    // slot -> (real-tile index rt, col-half ch); pair (d, d+8) same XCD
    const int grp = d >> 4, sub = d & 15;
    const int rt  = grp * 8 + (sub & 7);         // [0, 512)
    const int ch  = sub >> 3;

    // locate rt among real tiles: batch b, local tile lt (register-only scan)
    int b = -1, lt = 0, acc = 0;
    #pragma unroll
    for (int bb = 0; bb < NB; ++bb) {
        int rb = (seqlen[bb] + 63) >> 6;         // real tiles in batch bb
        if (rt >= acc && rt < acc + rb) { b = bb; lt = rt - acc; }
        acc += rb;
    }

    if (b >= 0) {                                 // ---- real GEMM block ----
        const int tok0 = (b << 11) + (lt << 6);
        const int sl0  = seqlen[b];

        // -- A: id, then issue the ENTIRE gather burst (20 loads, no VALU) --
        const int token_a = tok0 + wave * 16 + fr;
        const int id = ids[token_a];
        const float* __restrict__ rp = embed + (long long)id * E;

        f32x4 r0[9], r1[9], t0v, t1v;
        #pragma unroll
        for (int s = 0; s < 9; ++s) {
            const int kb = s * 32 + kg * 8;       // <= 280; ends 287 < 300
            r0[s] = *(const f32x4*)(rp + kb);
            r1[s] = *(const f32x4*)(rp + kb + 4);
        }
        {   // tail loads: valid k 288..299, exact bounds
            f32x4 z4 = {0.f, 0.f, 0.f, 0.f};
            t0v = z4; t1v = z4;
            if (kg == 0)      { t0v = *(const f32x4*)(rp + 288); t1v = *(const f32x4*)(rp + 292); }
            else if (kg == 1) { t0v = *(const f32x4*)(rp + 296); }
        }

        // -- stage W rows [ch*64, +64) -> LDS fragment-major (overlaps gather) --
        const int R0 = ch * 64;
        #pragma unroll
        for (int i = 0; i < 20; ++i) {
            int g4 = tid + i * 256;               // [0, 5120) quads
            int r  = g4 / 80;
            int c4 = g4 - r * 80;
            int c0 = c4 * 4;                      // {0,4,...,316}
            f32x4 v = {0.f, 0.f, 0.f, 0.f};
            if (c0 < 300)                         // c0 <= 296: reads 296..299 exact
                v = *(const f32x4*)(Wf + (long long)(R0 + r) * E + c0);
            int s   = c0 >> 5;
            int kgg = (c0 & 31) >> 3;
            int h   = (c0 >> 2) & 1;
            int ni  = r >> 4;
            int fr2 = r & 15;
            int off = (((s * 4 + ni) * 16 + fr2) << 6) + (kgg << 4) + (h << 3);
            *(bf16x4*)(Wl + off) = cvt4(v);
        }

        // -- convert the gather burst to bf16 fragments --
        bf16x8 av[10];
        #pragma unroll
        for (int s = 0; s < 9; ++s) av[s] = cvt8(r0[s], r1[s]);
        av[9] = cvt8(t0v, t1v);
        __syncthreads();

        // -- MFMA: 10 k-steps x 4 ni, B from LDS (conflict-free b128) --
        f32x4 acc4[4];
        #pragma unroll
        for (int ni = 0; ni < 4; ++ni) acc4[ni] = (f32x4){0.f, 0.f, 0.f, 0.f};

        #pragma unroll
        for (int s = 0; s < 10; ++s) {
            #pragma unroll
            for (int ni = 0; ni < 4; ++ni) {
                bf16x8 bv = *(const bf16x8*)(Wl + ((((s * 4 + ni) * 16 + fr) << 6) + (kg << 4)));
                acc4[ni] = __builtin_amdgcn_mfma_f32_16x16x32_bf16(av[s], bv, acc4[ni], 0, 0, 0);
            }
        }

        // -- epilogue: +bias, per-row seq-mask, store --
        // C/D layout: col(=W row -> P) = lane&15, row(=token) = (lane>>4)*4 + j
        float bs[4];
        #pragma unroll
        for (int ni = 0; ni < 4; ++ni) bs[ni] = bias[ch * 64 + ni * 16 + fr];

        #pragma unroll
        for (int j = 0; j < 4; ++j) {
            int orow  = wave * 16 + kg * 4 + j;
            int token = tok0 + orow;
            int t     = token & (S - 1);
            bool valid = (t < sl0);
            #pragma unroll
            for (int ni = 0; ni < 4; ++ni) {
                float v = valid ? (acc4[ni][j] + bs[ni]) : 0.0f;
                out[(long long)token * P + ch * 64 + ni * 16 + fr] = v;
            }
        }
    }

    // ---- zero-fill share (ALL blocks, exactly even split) ----
    int rb0  = (seqlen[0]  + 63) >> 6,  rb1  = (seqlen[1]  + 63) >> 6,
        rb2  = (seqlen[2]  + 63) >> 6,  rb3  = (seqlen[3]  + 63) >> 6,
        rb4  = (seqlen[4]  + 63) >> 6,  rb5  = (seqlen[5]  + 63) >> 6,
        rb6  = (seqlen[6]  + 63) >> 6,  rb7  = (seqlen[7]  + 63) >> 6,
        rb8  = (seqlen[8]  + 63) >> 6,  rb9  = (seqlen[9]  + 63) >> 6,
        rb10 = (seqlen[10] + 63) >> 6,  rb11 = (seqlen[11] + 63) >> 6,
        rb12 = (seqlen[12] + 63) >> 6,  rb13 = (seqlen[13] + 63) >> 6,
        rb14 = (seqlen[14] + 63) >> 6,  rb15 = (seqlen[15] + 63) >> 6;
    int zp0 = 0;
    int zp1  = zp0  + ((S - (rb0  << 6)) << 5);
    int zp2  = zp1  + ((S - (rb1  << 6)) << 5);
    int zp3  = zp2  + ((S - (rb2  << 6)) << 5);
    int zp4  = zp3  + ((S - (rb3  << 6)) << 5);
    int zp5  = zp4  + ((S - (rb4  << 6)) << 5);
    int zp6  = zp5  + ((S - (rb5  << 6)) << 5);
    int zp7  = zp6  + ((S - (rb6  << 6)) << 5);
    int zp8  = zp7  + ((S - (rb7  << 6)) << 5);
    int zp9  = zp8  + ((S - (rb8  << 6)) << 5);
    int zp10 = zp9  + ((S - (rb9  << 6)) << 5);
    int zp11 = zp10 + ((S - (rb10 << 6)) << 5);
    int zp12 = zp11 + ((S - (rb11 << 6)) << 5);
    int zp13 = zp12 + ((S - (rb12 << 6)) << 5);
    int zp14 = zp13 + ((S - (rb13 << 6)) << 5);
    int zp15 = zp14 + ((S - (rb14 << 6)) << 5);
    int zp16 = zp15 + ((S - (rb15 << 6)) << 5);

    const int zq  = zp16;
    const int per = (zq + 1023) >> 10;           // quads per block
    int q0 = d * per;
    int q1 = q0 + per; if (q1 > zq) q1 = zq;

    for (int q = q0 + tid; q < q1; q += 256) {
        int base = 0, tk0 = 0;
        #define ZSEL(BB, LO, HI, RB) \
            if (q >= (LO) && q < (HI)) { base = (LO); tk0 = ((BB) << 11) + ((RB) << 6); }
        ZSEL(0,  zp0,  zp1,  rb0)  ZSEL(1,  zp1,  zp2,  rb1)
        ZSEL(2,  zp2,  zp3,  rb2)  ZSEL(3,  zp3,  zp4,  rb3)
        ZSEL(4,  zp4,  zp5,  rb4)  ZSEL(5,  zp5,  zp6,  rb5)
        ZSEL(6,  zp6,  zp7,  rb6)  ZSEL(7,  zp7,  zp8,  rb7)
        ZSEL(8,  zp8,  zp9,  rb8)  ZSEL(9,  zp9,  zp10, rb9)
        ZSEL(10, zp10, zp11, rb10) ZSEL(11, zp11, zp12, rb11)
        ZSEL(12, zp12, zp13, rb12) ZSEL(13, zp13, zp14, rb13)
        ZSEL(14, zp14, zp15, rb14) ZSEL(15, zp15, zp16, rb15)
        #undef ZSEL
        int lq    = q - base;
        int token = tk0 + (lq >> 5);
        int c     = (lq & 31) << 2;
        *(f32x4*)(out + (long long)token * P + c) = (f32x4){0.f, 0.f, 0.f, 0.f};
    }
}

extern "C" void kernel_launch(void* const* d_in, const int* in_sizes, int n_in,
                              void* d_out, int out_size, void* d_ws, size_t ws_size,
                              hipStream_t stream) {
    const int*   ids    = (const int*)d_in[0];
    const int*   sl     = (const int*)d_in[1];
    const float* embed  = (const float*)d_in[2];
    const float* W      = (const float*)d_in[3];
    const float* bias   = (const float*)d_in[4];
    float*       out    = (float*)d_out;

    ft_main<<<(BS / TM) * 2, 256, 0, stream>>>(ids, sl, embed, W, bias, out);
}